// Round 16
// baseline (858.363 us; speedup 1.0000x reference)
//
#include <hip/hip_runtime.h>
#include <hip/hip_bf16.h>
#include <stdint.h>

// Lorenz Euler integration: strictly serial 3999-step recurrence.
// Measured model (rounds 3/11/14): single wave at DVFS idle clock
// (~1.25 GHz), ~2.5 cy per issued instruction -> ~13 instr/step -> 110 us.
// Lever tested this round: HEATER waves raise the DVFS clock while the
// serial wave (block 0, lane 0, s_setprio(3)) runs the recurrence.
// Heaters spin dependent FMAs and exit when block 0 sets a device-scope
// flag in d_ws (poisoned 0xAA != 1, no init needed; bounded 512 chunks).

#define LORENZ_DT 0.01f

__device__ __forceinline__ void lorenz_serial_core(const float* __restrict__ sigma,
                                                   const float* __restrict__ rho,
                                                   const float* __restrict__ beta,
                                                   const float* __restrict__ stats,
                                                   float* __restrict__ out, int n_t) {
    const float s = sigma[0];
    const float r = rho[0];
    const float b = beta[0];

    const float dts = LORENZ_DT * s;        // DT*s
    const float cx  = 1.0f - dts;           // 1 - DT*s
    const float cy  = 1.0f - LORENZ_DT;     // 1 - DT
    const float cz  = 1.0f - LORENZ_DT * b; // 1 - DT*b

    float x = stats[0];
    float y = stats[1];
    float z = stats[2];

    out[0] = x; out[1] = y; out[2] = z;

    const int n_steps = n_t - 1;
    float* p = out + 3;
    #pragma unroll 4
    for (int i = 0; i < n_steps; ++i) {
        const float rz  = r - z;
        const float dtx = LORENZ_DT * x;
        const float xy  = x * y;
        const float nx = fmaf(dts, y, cx * x);
        const float ny = fmaf(dtx, rz, cy * y);
        const float nz = fmaf(LORENZ_DT, xy, cz * z);
        x = nx; y = ny; z = nz;
        p[0] = x; p[1] = y; p[2] = z;
        p += 3;
    }
}

// Plain variant (fallback when ws_size < 64): identical to the 110.9 us
// round-3 kernel.
__global__ void lorenz_plain(const float* __restrict__ sigma,
                             const float* __restrict__ rho,
                             const float* __restrict__ beta,
                             const float* __restrict__ stats,
                             float* __restrict__ out, int n_t) {
    if (threadIdx.x != 0 || blockIdx.x != 0) return;
    lorenz_serial_core(sigma, rho, beta, stats, out, n_t);
}

// Heated variant: block 0 = serial work at prio 3; blocks 1..N-1 spin FMAs
// to hold the DVFS clock up, polling the done-flag with device-scope loads.
__global__ void lorenz_heated(const float* __restrict__ sigma,
                              const float* __restrict__ rho,
                              const float* __restrict__ beta,
                              const float* __restrict__ stats,
                              float* __restrict__ out, int n_t,
                              int* __restrict__ flag, float* __restrict__ ws_f) {
    if (blockIdx.x == 0) {
        // Whole wave raises priority (SALU, wave-level); only lane 0 works.
        __builtin_amdgcn_s_setprio(3);
        if (threadIdx.x == 0) {
            lorenz_serial_core(sigma, rho, beta, stats, out, n_t);
            __hip_atomic_store(flag, 1, __ATOMIC_RELEASE, __HIP_MEMORY_SCOPE_AGENT);
        }
        return;
    }

    // Heater: two interleaved dependent FMA chains (~full VALU duty).
    // Poll issued BEFORE the FMA block so its latency hides under the math.
    float a = (float)(threadIdx.x + 1) * 1e-8f;
    float c = (float)(blockIdx.x & 1023) * 1e-9f + 1e-9f;
    float va = a, vb = a * 0.5f;
    for (int chunk = 0; chunk < 512; ++chunk) {
        const int done = __hip_atomic_load(flag, __ATOMIC_ACQUIRE, __HIP_MEMORY_SCOPE_AGENT);
        #pragma unroll
        for (int i = 0; i < 128; ++i) {
            va = fmaf(va, 1.0000001f, c);
            vb = fmaf(vb, 0.9999999f, c);
        }
        if (done == 1) break;
    }
    // Keep the chains alive; condition is never true at runtime.
    if (va + vb == 123456.789f) ws_f[4] = va;
}

extern "C" void kernel_launch(void* const* d_in, const int* in_sizes, int n_in,
                              void* d_out, int out_size, void* d_ws, size_t ws_size,
                              hipStream_t stream) {
    const float* t     = (const float*)d_in[0];  // unused beyond its length
    const float* sigma = (const float*)d_in[1];
    const float* rho   = (const float*)d_in[2];
    const float* beta  = (const float*)d_in[3];
    const float* stats = (const float*)d_in[4];
    float* out = (float*)d_out;
    (void)t; (void)out_size;

    const int n_t = in_sizes[0];  // 4000 time points -> 3999 steps

    if (ws_size >= 64) {
        // 1 serial block + 2047 heater blocks (1 wave each; ~8 waves/CU).
        lorenz_heated<<<2048, 64, 0, stream>>>(sigma, rho, beta, stats, out, n_t,
                                               (int*)d_ws, (float*)d_ws);
    } else {
        lorenz_plain<<<1, 64, 0, stream>>>(sigma, rho, beta, stats, out, n_t);
    }
}

// Round 17
// 129.189 us; speedup vs baseline: 6.6442x; 6.6442x over previous
//
#include <hip/hip_runtime.h>
#include <hip/hip_bf16.h>
#include <stdint.h>

// Lorenz Euler integration, two-pass checkpoint scheme.
// Model (rounds 3/11/14/16): single serial wave is ISSUE-bound (~2.7 cy per
// issued instruction at idle clock); stores/movs cost like math. Round 16
// proved heaters can't raise the clock usefully (flag poll starved, 7.5x
// regression). So: cut issued instructions on the serial path to the bare
// 9-VALU step math.
//   Pass 1: lane 0 integrates 63 chunks x 63 steps storeless, one LDS
//           checkpoint per chunk (ds_write off the critical chain).
//   Pass 2: 64 lanes re-integrate one chunk each in parallel from their
//           checkpoint, writing rows. Bitwise-identical fp32 sequence.
// Rows: row j = state after j steps; lane L covers rows 63L..63L+62.
// 64*63 = 4032 >= 4000 rows; lane-63 tail predicated.

#define LORENZ_DT 0.01f
#define CHUNK 63
#define NLANES 64

// Same math/op-order as the verified rounds 3/11/14 (absmax 3.9e-3).
#define LORENZ_STEP() do {                              \
        const float rz  = r - z;                        \
        const float dtx = LORENZ_DT * x;                \
        const float xy  = x * y;                        \
        const float nx = fmaf(dts, y, cx * x);          \
        const float ny = fmaf(dtx, rz, cy * y);         \
        const float nz = fmaf(LORENZ_DT, xy, cz * z);   \
        x = nx; y = ny; z = nz;                         \
    } while (0)

__global__ __launch_bounds__(64, 1) void lorenz_two_pass(
        const float* __restrict__ sigma, const float* __restrict__ rho,
        const float* __restrict__ beta, const float* __restrict__ stats,
        float* __restrict__ out, int n_t) {
    __shared__ float4 ckpt[NLANES];
    const int lane = threadIdx.x;

    const float s = sigma[0];
    const float r = rho[0];
    const float b = beta[0];
    const float dts = LORENZ_DT * s;        // DT*s
    const float cx  = 1.0f - dts;           // 1 - DT*s
    const float cy  = 1.0f - LORENZ_DT;     // 1 - DT
    const float cz  = 1.0f - LORENZ_DT * b; // 1 - DT*b

    if (lane == 0) {
        // Pass 1: storeless serial integration; 9 VALU/step, no addressing.
        float x = stats[0], y = stats[1], z = stats[2];
        ckpt[0] = make_float4(x, y, z, 0.0f);
        for (int c = 1; c < NLANES; ++c) {
            #pragma unroll
            for (int k = 0; k < CHUNK; ++k) { LORENZ_STEP(); }
            ckpt[c] = make_float4(x, y, z, 0.0f);
        }
    }
    __syncthreads();

    // Pass 2: each lane re-integrates its chunk from its checkpoint.
    const float4 st = ckpt[lane];
    float x = st.x, y = st.y, z = st.z;
    int row = lane * CHUNK;
    if (row < n_t) {
        float* p = out + (size_t)row * 3;
        p[0] = x; p[1] = y; p[2] = z;
    }
    for (int k = 1; k < CHUNK; ++k) {
        LORENZ_STEP();
        ++row;
        if (row < n_t) {
            float* p = out + (size_t)row * 3;
            p[0] = x; p[1] = y; p[2] = z;
        }
    }
}

// Fallback for shapes outside the two-pass coverage (n_t > 4032): the plain
// round-3 serial kernel.
__global__ void lorenz_plain(const float* __restrict__ sigma,
                             const float* __restrict__ rho,
                             const float* __restrict__ beta,
                             const float* __restrict__ stats,
                             float* __restrict__ out, int n_t) {
    if (threadIdx.x != 0 || blockIdx.x != 0) return;
    const float s = sigma[0];
    const float r = rho[0];
    const float b = beta[0];
    const float dts = LORENZ_DT * s;
    const float cx  = 1.0f - dts;
    const float cy  = 1.0f - LORENZ_DT;
    const float cz  = 1.0f - LORENZ_DT * b;
    float x = stats[0], y = stats[1], z = stats[2];
    out[0] = x; out[1] = y; out[2] = z;
    float* p = out + 3;
    for (int i = 0; i < n_t - 1; ++i) {
        LORENZ_STEP();
        p[0] = x; p[1] = y; p[2] = z;
        p += 3;
    }
}

extern "C" void kernel_launch(void* const* d_in, const int* in_sizes, int n_in,
                              void* d_out, int out_size, void* d_ws, size_t ws_size,
                              hipStream_t stream) {
    const float* t     = (const float*)d_in[0];  // unused beyond its length
    const float* sigma = (const float*)d_in[1];
    const float* rho   = (const float*)d_in[2];
    const float* beta  = (const float*)d_in[3];
    const float* stats = (const float*)d_in[4];
    float* out = (float*)d_out;
    (void)t; (void)d_ws; (void)ws_size; (void)out_size;

    const int n_t = in_sizes[0];  // 4000 time points -> 3999 steps

    if (n_t >= 2 && n_t <= NLANES * CHUNK + 1) {
        lorenz_two_pass<<<1, 64, 0, stream>>>(sigma, rho, beta, stats, out, n_t);
    } else {
        lorenz_plain<<<1, 64, 0, stream>>>(sigma, rho, beta, stats, out, n_t);
    }
}

// Round 18
// 118.652 us; speedup vs baseline: 7.2343x; 1.0888x over previous
//
#include <hip/hip_runtime.h>
#include <hip/hip_bf16.h>
#include <stdint.h>

// Lorenz Euler integration, two-pass checkpoint scheme (round 17: 85.5 us).
// Pass 1 (lane 0, serial 3969 steps) is issue-bound: ~26 cy/step at 9 VALU.
// This round cuts pass 1 to 6 issue slots/step:
//   w-trick:  w = fma(-DT, z, DT*r)  == DT*(r-z)   (saves rz+dtx)
//   packed:   (nx,ny) via v_pk_mul_f32 + v_pk_fma_f32 with op_sel
//     P=(x,y), D=(dts,w), M=pk_mul((cx,cy),P)=(cx*x, cy*y)
//     pk_fma op_sel:[0,1,0] op_sel_hi:[1,0,1]:
//       P.lo = dts*y + cx*x = nx ;  P.hi = w*x + cy*y = ny
//   z-path scalar: czz = cz*z ; z = fma(DT, x*y, czz)
// Pass 2 unchanged (scalar, verified): lane L re-integrates rows 63L..63L+62
// from its LDS checkpoint. Lane 0 starts from stats exactly; an asm bug in
// pass 1 corrupts rows >=63 -> caught by harness, never silent.

#define LORENZ_DT 0.01f
#define CHUNK 63
#define NLANES 64

typedef float v2f __attribute__((ext_vector_type(2)));

// Scalar step, same math/op-order as verified rounds 3..17.
#define LORENZ_STEP_SCALAR() do {                       \
        const float rz  = r - z;                        \
        const float dtx = LORENZ_DT * x;                \
        const float xy  = x * y;                        \
        const float nx = fmaf(dts, y, cx * x);          \
        const float ny = fmaf(dtx, rz, cy * y);         \
        const float nz = fmaf(LORENZ_DT, xy, cz * z);   \
        x = nx; y = ny; z = nz;                         \
    } while (0)

__global__ __launch_bounds__(64, 1) void lorenz_two_pass(
        const float* __restrict__ sigma, const float* __restrict__ rho,
        const float* __restrict__ beta, const float* __restrict__ stats,
        float* __restrict__ out, int n_t) {
    __shared__ float4 ckpt[NLANES];
    const int lane = threadIdx.x;

    const float s = sigma[0];
    const float r = rho[0];
    const float b = beta[0];
    const float dts = LORENZ_DT * s;        // DT*s
    const float cx  = 1.0f - dts;           // 1 - DT*s
    const float cy  = 1.0f - LORENZ_DT;     // 1 - DT
    const float cz  = 1.0f - LORENZ_DT * b; // 1 - DT*b

    if (lane == 0) {
        // Pass 1: serial, 6 issue slots/step (2 packed + 4 scalar).
        const float dtr   = LORENZ_DT * r;
        const float negDT = -LORENZ_DT;
        v2f P; P.x = stats[0]; P.y = stats[1];   // (x, y)
        float z = stats[2];
        v2f C1; C1.x = cx; C1.y = cy;            // (cx, cy) constant pair
        v2f D;  D.x = dts; D.y = 0.0f;           // (dts, w); w updated per step
        ckpt[0] = make_float4(P.x, P.y, z, 0.0f);
        for (int c = 1; c < NLANES; ++c) {
            #pragma unroll
            for (int k = 0; k < CHUNK; ++k) {
                D.y = fmaf(negDT, z, dtr);       // w = DT*(r-z)
                const float xy = P.x * P.y;
                v2f M;
                asm("v_pk_mul_f32 %0, %1, %2"
                    : "=v"(M) : "v"(C1), "v"(P));            // (cx*x, cy*y)
                asm("v_pk_fma_f32 %0, %1, %2, %3 op_sel:[0,1,0] op_sel_hi:[1,0,1]"
                    : "=v"(P) : "v"(D), "v"(P), "v"(M));      // (nx, ny)
                const float czz = cz * z;
                z = fmaf(LORENZ_DT, xy, czz);
            }
            ckpt[c] = make_float4(P.x, P.y, z, 0.0f);
        }
    }
    __syncthreads();

    // Pass 2: each lane re-integrates its chunk from its checkpoint (scalar).
    const float4 st = ckpt[lane];
    float x = st.x, y = st.y, z = st.z;
    int row = lane * CHUNK;
    if (row < n_t) {
        float* p = out + (size_t)row * 3;
        p[0] = x; p[1] = y; p[2] = z;
    }
    for (int k = 1; k < CHUNK; ++k) {
        LORENZ_STEP_SCALAR();
        ++row;
        if (row < n_t) {
            float* p = out + (size_t)row * 3;
            p[0] = x; p[1] = y; p[2] = z;
        }
    }
}

// Fallback for shapes outside two-pass coverage (n_t > 4032): plain serial.
__global__ void lorenz_plain(const float* __restrict__ sigma,
                             const float* __restrict__ rho,
                             const float* __restrict__ beta,
                             const float* __restrict__ stats,
                             float* __restrict__ out, int n_t) {
    if (threadIdx.x != 0 || blockIdx.x != 0) return;
    const float s = sigma[0];
    const float r = rho[0];
    const float b = beta[0];
    const float dts = LORENZ_DT * s;
    const float cx  = 1.0f - dts;
    const float cy  = 1.0f - LORENZ_DT;
    const float cz  = 1.0f - LORENZ_DT * b;
    float x = stats[0], y = stats[1], z = stats[2];
    out[0] = x; out[1] = y; out[2] = z;
    float* p = out + 3;
    for (int i = 0; i < n_t - 1; ++i) {
        LORENZ_STEP_SCALAR();
        p[0] = x; p[1] = y; p[2] = z;
        p += 3;
    }
}

extern "C" void kernel_launch(void* const* d_in, const int* in_sizes, int n_in,
                              void* d_out, int out_size, void* d_ws, size_t ws_size,
                              hipStream_t stream) {
    const float* t     = (const float*)d_in[0];  // unused beyond its length
    const float* sigma = (const float*)d_in[1];
    const float* rho   = (const float*)d_in[2];
    const float* beta  = (const float*)d_in[3];
    const float* stats = (const float*)d_in[4];
    float* out = (float*)d_out;
    (void)t; (void)d_ws; (void)ws_size; (void)out_size;

    const int n_t = in_sizes[0];  // 4000 time points -> 3999 steps

    if (n_t >= 2 && n_t <= NLANES * CHUNK + 1) {
        lorenz_two_pass<<<1, 64, 0, stream>>>(sigma, rho, beta, stats, out, n_t);
    } else {
        lorenz_plain<<<1, 64, 0, stream>>>(sigma, rho, beta, stats, out, n_t);
    }
}